// Round 9
// baseline (228.950 us; speedup 1.0000x reference)
//
#include <hip/hip_runtime.h>
#include <stdint.h>

// Kalman filter scan: B=128, T=256, V=256.
// R8 lesson: 1 thread/track = 512 waves on 1024 SIMDs -- occupancy-bound;
// per-wave ILP pipelining plateaued at ~45us. This round creates T-parallelism
// EXACTLY:
//  * P/K recursion depends only on the label (mask) sequence -> a thread for
//    chunk c replays it from t=0 with cheap warm-up steps (label-only loads,
//    ~15 VALU) -- bit-identical P and K, no convergence approximation.
//  * Given K_t, the state recursion is affine: [x;v]' = A_t [x;v] + K_t z_t.
//    Each (chunk, track) thread accumulates its chunk's affine map
//    (M 2x2, d per axis) over 32 real steps -> 8 floats to workspace.
//  * Kernel 2 composes the 8 chunk maps per track (starting state = 0) and
//    writes (1, x, y).
// 8 chunks x 32768 tracks = 4096 waves = 4 waves/SIMD: real TLP latency
// hiding, so plain HIP loads are fine.

#define KF_B 128
#define KF_T 256
#define KF_V 256
#define KF_C 8     // chunks
#define KF_L 32    // steps per chunk
#define KF_NT (KF_B * KF_V)   // 32768 tracks

// --- P/K recursion shared by warm-up and full steps (identical fp ops) ---
#define KF_PK(label)                                                    \
    const float q00 = p00 + 2.f * p01 + p11 + 0.01f;                    \
    const float q01 = p01 + p11;                                        \
    const float q11 = p11 + 0.01f;                                      \
    const float S = q00 + 1.f;                                          \
    const float m = ((label) != -1.0f) ? 1.0f : 0.0f;                   \
    const float is = m * __builtin_amdgcn_rcpf(S);                      \
    const float K0 = q00 * is;                                          \
    const float K1 = q01 * is;                                          \
    p00 = q00 - K0 * q00;                                               \
    p01 = q01 - K0 * q01;                                               \
    p11 = q11 - K1 * q01;

__global__ __launch_bounds__(64) void kf_scan(const float* __restrict__ batch,
                                              float* __restrict__ ws) {
    // Interleave chunks across consecutive blocks for CU load balance
    // (chunk 7 does ~3.5x chunk 0's work).
    const int blk = blockIdx.x;
    const int chunk = blk & (KF_C - 1);          // uniform per block
    const int trackblk = blk >> 3;
    const int track = trackblk * 64 + threadIdx.x;   // 0..32767
    const int b = track >> 8;
    const int v = track & (KF_V - 1);

    const float* __restrict__ base =
        batch + ((size_t)b * KF_T * KF_V + v) * 3;   // + t*768 per step
    const int stride = KF_V * 3;                     // 768 floats

    // covariance recursion state (shared by both axes)
    float p00 = 1000.f, p01 = 0.f, p11 = 1000.f;

    // ---- warm-up: replay P/K exactly from t=0 (label-only loads) ----
    const int warmT = KF_L * chunk;
    const float* p = base;
    for (int t = 0; t < warmT; ++t) {
        const float label = p[0];
        p += stride;
        KF_PK(label);
    }

    // ---- real steps: accumulate chunk affine map ----
    // [x;v]_end = M [x;v]_start + d   (per axis; M shared, d per axis)
    float m00 = 1.f, m01 = 0.f, m10 = 0.f, m11 = 1.f;
    float d0p = 0.f, d0v = 0.f, d1p = 0.f, d1v = 0.f;

    for (int t = 0; t < KF_L; ++t) {
        const float label = p[0];
        const float z0 = p[1];
        const float z1 = p[2];
        p += stride;
        KF_PK(label);
        const float a = 1.f - K0;
        // M' = A*M, A = [[a,a],[-K1,1-K1]]
        const float t00 = m00 + m10;
        const float t01 = m01 + m11;
        m00 = a * t00;
        m01 = a * t01;
        m10 = m10 - K1 * t00;
        m11 = m11 - K1 * t01;
        // d' = A*d + [K0 z; K1 z]
        const float s0 = d0p + d0v;
        d0p = a * s0 + K0 * z0;
        d0v = d0v + K1 * (z0 - s0);
        const float s1 = d1p + d1v;
        d1p = a * s1 + K0 * z1;
        d1v = d1v + K1 * (z1 - s1);
    }

    // ---- write chunk map: [chunk][track][8] ----
    float* w = ws + ((size_t)chunk * KF_NT + track) * 8;
    float4 w0 = make_float4(m00, m01, m10, m11);
    float4 w1 = make_float4(d0p, d0v, d1p, d1v);
    *(float4*)(w) = w0;
    *(float4*)(w + 4) = w1;
}

__global__ __launch_bounds__(64) void kf_compose(const float* __restrict__ ws,
                                                 float* __restrict__ out) {
    const int track = blockIdx.x * 64 + threadIdx.x;   // 0..32767
    float x0 = 0.f, v0 = 0.f, x1 = 0.f, v1 = 0.f;
#pragma unroll
    for (int c = 0; c < KF_C; ++c) {
        const float* w = ws + ((size_t)c * KF_NT + track) * 8;
        const float4 a = *(const float4*)(w);
        const float4 d = *(const float4*)(w + 4);
        const float nx0 = a.x * x0 + a.y * v0 + d.x;
        const float nv0 = a.z * x0 + a.w * v0 + d.y;
        const float nx1 = a.x * x1 + a.y * v1 + d.z;
        const float nv1 = a.z * x1 + a.w * v1 + d.w;
        x0 = nx0; v0 = nv0; x1 = nx1; v1 = nv1;
    }
    float* o = out + (size_t)track * 3;
    o[0] = 1.0f;
    o[1] = x0;
    o[2] = x1;
}

extern "C" void kernel_launch(void* const* d_in, const int* in_sizes, int n_in,
                              void* d_out, int out_size, void* d_ws, size_t ws_size,
                              hipStream_t stream) {
    (void)in_sizes; (void)n_in; (void)ws_size; (void)out_size;
    const float* batch = (const float*)d_in[0];
    float* out = (float*)d_out;
    float* ws = (float*)d_ws;   // needs KF_C*KF_NT*8*4 = 8.4 MB

    kf_scan<<<KF_C * KF_NT / 64, 64, 0, stream>>>(batch, ws);      // 4096 blocks
    kf_compose<<<KF_NT / 64, 64, 0, stream>>>(ws, out);            // 512 blocks
}

// Round 10
// 159.443 us; speedup vs baseline: 1.4359x; 1.4359x over previous
//
#include <hip/hip_runtime.h>
#include <stdint.h>

// Kalman filter scan: B=128, T=256, V=256. T-parallel affine-scan (R9 machinery,
// correctness-verified) with LOCAL warm-up instead of exact replay-from-0:
//
//  * R9 lesson: exact replay made 8 chunk-phases walk 8 different t-regions
//    concurrently -> L3 thrash (FETCH 49->221 MB, 1.9 TB/s, 123 us).
//  * Riccati forgetting: each observed step contracts P-discrepancy by
//    ~(1-K)^2 ~= 0.15. Warm-up over the 32 steps immediately BEFORE the chunk
//    with uninformative init P=1000*I gives P error ~1e-10 at chunk start
//    (P(<6 observed of 32) ~ 1e-15 at miss-rate 0.2 -- zero over 262k threads).
//    Chunk 0 is exact (no warm-up, true P0).
//  * Locality: chunk c's warm-up region == chunk c-1's real region, read
//    concurrently -> L2/L3 hits; unique HBM traffic stays ~100 MB.
//
// 8 chunks x 32768 tracks = 4096 waves = 4 waves/SIMD (vs 0.5 in R1-R8).

#define KF_B 128
#define KF_T 256
#define KF_V 256
#define KF_C 8     // chunks
#define KF_L 32    // steps per chunk (and warm-up length)
#define KF_NT (KF_B * KF_V)   // 32768 tracks

// --- P/K recursion shared by warm-up and full steps (identical fp ops) ---
#define KF_PK(label)                                                    \
    const float q00 = p00 + 2.f * p01 + p11 + 0.01f;                    \
    const float q01 = p01 + p11;                                        \
    const float q11 = p11 + 0.01f;                                      \
    const float S = q00 + 1.f;                                          \
    const float m = ((label) != -1.0f) ? 1.0f : 0.0f;                   \
    const float is = m * __builtin_amdgcn_rcpf(S);                      \
    const float K0 = q00 * is;                                          \
    const float K1 = q01 * is;                                          \
    p00 = q00 - K0 * q00;                                               \
    p01 = q01 - K0 * q01;                                               \
    p11 = q11 - K1 * q01;

__global__ __launch_bounds__(64) void kf_scan(const float* __restrict__ batch,
                                              float* __restrict__ ws) {
    // Interleave chunks across consecutive blocks: all 8 phases co-resident
    // per CU neighborhood -> chunk c's warm-up reads hit lines chunk c-1 is
    // reading as real data.
    const int blk = blockIdx.x;
    const int chunk = blk & (KF_C - 1);              // uniform per block
    const int track = (blk >> 3) * 64 + threadIdx.x; // 0..32767
    const int b = track >> 8;
    const int v = track & (KF_V - 1);

    const int stride = KF_V * 3;                     // 768 floats per t
    const float* __restrict__ base =
        batch + ((size_t)b * KF_T * KF_V + v) * 3;

    // covariance recursion state (shared by both axes)
    float p00 = 1000.f, p01 = 0.f, p11 = 1000.f;

    const float* p;
    if (chunk != 0) {
        // ---- local warm-up: 32 steps before the chunk, label-only loads ----
        p = base + (size_t)(KF_L * (chunk - 1)) * stride;
#pragma unroll 4
        for (int t = 0; t < KF_L; ++t) {
            const float label = p[0];
            p += stride;
            KF_PK(label);
        }
        // p now points at the chunk's real region: base + 32*chunk*stride
    } else {
        p = base;   // chunk 0: exact init, no warm-up
    }

    // ---- real steps: accumulate chunk affine map ----
    // [x;v]_end = M [x;v]_start + d   (per axis; M shared, d per axis)
    float m00 = 1.f, m01 = 0.f, m10 = 0.f, m11 = 1.f;
    float d0p = 0.f, d0v = 0.f, d1p = 0.f, d1v = 0.f;

#pragma unroll 4
    for (int t = 0; t < KF_L; ++t) {
        const float label = p[0];
        const float z0 = p[1];
        const float z1 = p[2];
        p += stride;
        KF_PK(label);
        const float a = 1.f - K0;
        // M' = A*M, A = [[a,a],[-K1,1-K1]]
        const float t00 = m00 + m10;
        const float t01 = m01 + m11;
        m00 = a * t00;
        m01 = a * t01;
        m10 = m10 - K1 * t00;
        m11 = m11 - K1 * t01;
        // d' = A*d + K*z
        const float s0 = d0p + d0v;
        d0p = a * s0 + K0 * z0;
        d0v = d0v + K1 * (z0 - s0);
        const float s1 = d1p + d1v;
        d1p = a * s1 + K0 * z1;
        d1v = d1v + K1 * (z1 - s1);
    }

    // ---- write chunk map: [chunk][track][8] ----
    float* w = ws + ((size_t)chunk * KF_NT + track) * 8;
    *(float4*)(w)     = make_float4(m00, m01, m10, m11);
    *(float4*)(w + 4) = make_float4(d0p, d0v, d1p, d1v);
}

__global__ __launch_bounds__(64) void kf_compose(const float* __restrict__ ws,
                                                 float* __restrict__ out) {
    const int track = blockIdx.x * 64 + threadIdx.x;   // 0..32767
    float x0 = 0.f, v0 = 0.f, x1 = 0.f, v1 = 0.f;
#pragma unroll
    for (int c = 0; c < KF_C; ++c) {
        const float* w = ws + ((size_t)c * KF_NT + track) * 8;
        const float4 a = *(const float4*)(w);
        const float4 d = *(const float4*)(w + 4);
        const float nx0 = a.x * x0 + a.y * v0 + d.x;
        const float nv0 = a.z * x0 + a.w * v0 + d.y;
        const float nx1 = a.x * x1 + a.y * v1 + d.z;
        const float nv1 = a.z * x1 + a.w * v1 + d.w;
        x0 = nx0; v0 = nv0; x1 = nx1; v1 = nv1;
    }
    float* o = out + (size_t)track * 3;
    o[0] = 1.0f;
    o[1] = x0;
    o[2] = x1;
}

extern "C" void kernel_launch(void* const* d_in, const int* in_sizes, int n_in,
                              void* d_out, int out_size, void* d_ws, size_t ws_size,
                              hipStream_t stream) {
    (void)in_sizes; (void)n_in; (void)ws_size; (void)out_size;
    const float* batch = (const float*)d_in[0];
    float* out = (float*)d_out;
    float* ws = (float*)d_ws;   // needs KF_C*KF_NT*8*4 = 8.4 MB

    kf_scan<<<KF_C * KF_NT / 64, 64, 0, stream>>>(batch, ws);      // 4096 blocks
    kf_compose<<<KF_NT / 64, 64, 0, stream>>>(ws, out);            // 512 blocks
}

// Round 11
// 156.363 us; speedup vs baseline: 1.4642x; 1.0197x over previous
//
#include <hip/hip_runtime.h>
#include <stdint.h>

// Kalman filter scan: B=128, T=256, V=256. T-parallel affine-scan.
// R10 lesson: C=8 (4 waves/SIMD) scan ran ~53us -- still latency-limited
// (VALU work only ~5.5us, unique traffic ~100MB). This round:
//  * C=16 chunks x L=16 real steps, warm-up=16 -> 8192 waves = 8 waves/SIMD
//    (HW max; __launch_bounds__(64,8) caps VGPR at 64 to guarantee it).
//  * Warm-up numerics: chunk1's warm-up replays t=0..15 from the TRUE P0
//    (exact); chunks>=2: each observed warm-up step contracts P-discrepancy
//    ~0.15x; typical 13 observed -> 1e-11; 1e-7-tail (<=3 observed) -> ~0.02
//    state error, still < 0.063 threshold.
//  * float2 packing of the two axes / matrix rows -> v_pk_{add,mul,fma}_f32
//    (full-rate packed fp32 on CDNA): real step ~23 instrs vs ~35.
//  * chunk-interleaved block order: warm-up region == neighbor chunk's real
//    region, concurrently read -> L2/L3 hits (input fits in 256MB L3).

#define KF_B 128
#define KF_T 256
#define KF_V 256
#define KF_C 16    // chunks
#define KF_L 16    // real steps per chunk
#define KF_W 16    // warm-up steps
#define KF_NT (KF_B * KF_V)   // 32768 tracks

typedef float f2 __attribute__((ext_vector_type(2)));

// --- P/K recursion shared by warm-up and real steps (identical fp ops) ---
#define KF_PK(label)                                                    \
    const float q00 = p00 + 2.f * p01 + p11 + 0.01f;                    \
    const float q01 = p01 + p11;                                        \
    const float q11 = p11 + 0.01f;                                      \
    const float S = q00 + 1.f;                                          \
    const float m = ((label) != -1.0f) ? 1.0f : 0.0f;                   \
    const float is = m * __builtin_amdgcn_rcpf(S);                      \
    const float K0 = q00 * is;                                          \
    const float K1 = q01 * is;                                          \
    p00 = q00 - K0 * q00;                                               \
    p01 = q01 - K0 * q01;                                               \
    p11 = q11 - K1 * q01;

__global__ __launch_bounds__(64, 8) void kf_scan(const float* __restrict__ batch,
                                                 float* __restrict__ ws) {
    // chunk-interleaved: consecutive blocks = all 16 chunks of one track-group
    const int blk = blockIdx.x;
    const int chunk = blk & (KF_C - 1);               // uniform per block
    const int track = (blk >> 4) * 64 + threadIdx.x;  // 0..32767
    const int b = track >> 8;
    const int v = track & (KF_V - 1);

    const int stride = KF_V * 3;                      // 768 floats per t
    const float* __restrict__ base =
        batch + ((size_t)b * KF_T * KF_V + v) * 3;

    // covariance recursion state (shared by both axes)
    float p00 = 1000.f, p01 = 0.f, p11 = 1000.f;

    const float* p;
    if (chunk != 0) {
        // local warm-up: KF_W steps before the chunk, label-only loads
        p = base + (size_t)(KF_L * (chunk - 1)) * stride;
#pragma unroll 4
        for (int t = 0; t < KF_W; ++t) {
            const float label = p[0];
            p += stride;
            KF_PK(label);
        }
    } else {
        p = base;   // chunk 0: exact init, no warm-up
    }

    // ---- real steps: accumulate chunk affine map (packed fp32) ----
    // per axis: [x;v]_end = M [x;v]_start + d ; M shared, d packed over axes
    f2 mA = {1.f, 0.f};    // (m00, m01)
    f2 mB = {0.f, 1.f};    // (m10, m11)
    f2 dp = {0.f, 0.f};    // (d0_pos, d1_pos)
    f2 dv = {0.f, 0.f};    // (d0_vel, d1_vel)

#pragma unroll 4
    for (int t = 0; t < KF_L; ++t) {
        const float label = p[0];
        const f2 z = {p[1], p[2]};
        p += stride;
        KF_PK(label);
        const float a = 1.f - K0;
        // M' = A*M, A = [[a,a],[-K1,1-K1]]
        const f2 tm = mA + mB;
        mA = a * tm;
        mB = mB - K1 * tm;
        // d' = A*d + K*z (both axes at once)
        const f2 s = dp + dv;
        dp = a * s + K0 * z;
        dv = dv + K1 * (z - s);
    }

    // ---- write chunk map: [chunk][track][8] = m00,m01,m10,m11,dp0,dp1,dv0,dv1
    float* w = ws + ((size_t)chunk * KF_NT + track) * 8;
    *(float4*)(w)     = make_float4(mA.x, mA.y, mB.x, mB.y);
    *(float4*)(w + 4) = make_float4(dp.x, dp.y, dv.x, dv.y);
}

__global__ __launch_bounds__(64) void kf_compose(const float* __restrict__ ws,
                                                 float* __restrict__ out) {
    const int track = blockIdx.x * 64 + threadIdx.x;   // 0..32767
    f2 x = {0.f, 0.f};   // (x0, x1)
    f2 v = {0.f, 0.f};   // (v0, v1)
#pragma unroll
    for (int c = 0; c < KF_C; ++c) {
        const float* w = ws + ((size_t)c * KF_NT + track) * 8;
        const float4 a = *(const float4*)(w);
        const float4 d = *(const float4*)(w + 4);
        const f2 dpv = {d.x, d.y};
        const f2 dvv = {d.z, d.w};
        const f2 nx = a.x * x + a.y * v + dpv;
        const f2 nv = a.z * x + a.w * v + dvv;
        x = nx; v = nv;
    }
    float* o = out + (size_t)track * 3;
    o[0] = 1.0f;
    o[1] = x.x;
    o[2] = x.y;
}

extern "C" void kernel_launch(void* const* d_in, const int* in_sizes, int n_in,
                              void* d_out, int out_size, void* d_ws, size_t ws_size,
                              hipStream_t stream) {
    (void)in_sizes; (void)n_in; (void)ws_size; (void)out_size;
    const float* batch = (const float*)d_in[0];
    float* out = (float*)d_out;
    float* ws = (float*)d_ws;   // needs KF_C*KF_NT*8*4 = 16.8 MB

    kf_scan<<<KF_C * KF_NT / 64, 64, 0, stream>>>(batch, ws);      // 8192 blocks
    kf_compose<<<KF_NT / 64, 64, 0, stream>>>(ws, out);            // 512 blocks
}

// Round 12
// 155.800 us; speedup vs baseline: 1.4695x; 1.0036x over previous
//
#include <hip/hip_runtime.h>
#include <stdint.h>

// Kalman filter scan: B=128, T=256, V=256. T-parallel affine-scan.
//
// R11 lesson (cross-round invariant): R9/R10/R11 scans all served demand at
// ~3.7-4.0 TB/s (450MB/123us, 200MB/53us, 200MB/50us) regardless of occupancy
// -> throughput-bound on the cache system. Cause: chunk-interleaved order
// blk=g*16+c gives XCD=c%8, so chunk c+1's warm-up (which re-reads chunk c's
// real region) is ALWAYS cross-XCD -> L3-rate (~4 TB/s) service.
//
// This round, ONE change: chunk-major mapping blk=c*512+g -> XCD=g%8, i.e.
// all 16 chunks of a track-group on the SAME XCD. Warm-up reads then hit the
// neighbor chunk's freshly-fetched lines in the local L2 (~34 TB/s). Unique
// HBM stays ~100MB; the 100MB re-read moves L3 -> same-XCD L2.
//
// Kept from R11: C=16 x L=16, W=16 local warm-up (chunk1 exact from true P0;
// chunks>=2: each observed warm-up step contracts P-discrepancy ~0.15x;
// measured absmax 0.0078 << 0.063), packed-f2 axis math, 8 waves/SIMD.

#define KF_B 128
#define KF_T 256
#define KF_V 256
#define KF_C 16    // chunks
#define KF_L 16    // real steps per chunk
#define KF_W 16    // warm-up steps
#define KF_NT (KF_B * KF_V)   // 32768 tracks
#define KF_NG (KF_NT / 64)    // 512 track-groups (one block each per chunk)

typedef float f2 __attribute__((ext_vector_type(2)));

// --- P/K recursion shared by warm-up and real steps (identical fp ops) ---
#define KF_PK(label)                                                    \
    const float q00 = p00 + 2.f * p01 + p11 + 0.01f;                    \
    const float q01 = p01 + p11;                                        \
    const float q11 = p11 + 0.01f;                                      \
    const float S = q00 + 1.f;                                          \
    const float m = ((label) != -1.0f) ? 1.0f : 0.0f;                   \
    const float is = m * __builtin_amdgcn_rcpf(S);                      \
    const float K0 = q00 * is;                                          \
    const float K1 = q01 * is;                                          \
    p00 = q00 - K0 * q00;                                               \
    p01 = q01 - K0 * q01;                                               \
    p11 = q11 - K1 * q01;

__global__ __launch_bounds__(64, 8) void kf_scan(const float* __restrict__ batch,
                                                 float* __restrict__ ws) {
    // chunk-MAJOR mapping: XCD = blockIdx%8 = g%8 -> all chunks of a
    // track-group co-located on one XCD (L2 reuse between c+1 warm / c real).
    const int blk = blockIdx.x;
    const int chunk = blk >> 9;                       // 0..15, uniform
    const int g = blk & (KF_NG - 1);                  // 0..511
    const int track = g * 64 + threadIdx.x;           // 0..32767
    const int b = track >> 8;
    const int v = track & (KF_V - 1);

    const int stride = KF_V * 3;                      // 768 floats per t
    const float* __restrict__ base =
        batch + ((size_t)b * KF_T * KF_V + v) * 3;

    // covariance recursion state (shared by both axes)
    float p00 = 1000.f, p01 = 0.f, p11 = 1000.f;

    const float* p;
    if (chunk != 0) {
        // local warm-up: KF_W steps before the chunk, label-only loads
        p = base + (size_t)(KF_L * (chunk - 1)) * stride;
#pragma unroll 4
        for (int t = 0; t < KF_W; ++t) {
            const float label = p[0];
            p += stride;
            KF_PK(label);
        }
    } else {
        p = base;   // chunk 0: exact init, no warm-up
    }

    // ---- real steps: accumulate chunk affine map (packed fp32) ----
    f2 mA = {1.f, 0.f};    // (m00, m01)
    f2 mB = {0.f, 1.f};    // (m10, m11)
    f2 dp = {0.f, 0.f};    // (d0_pos, d1_pos)
    f2 dv = {0.f, 0.f};    // (d0_vel, d1_vel)

#pragma unroll 4
    for (int t = 0; t < KF_L; ++t) {
        const float label = p[0];
        const f2 z = {p[1], p[2]};
        p += stride;
        KF_PK(label);
        const float a = 1.f - K0;
        // M' = A*M, A = [[a,a],[-K1,1-K1]]
        const f2 tm = mA + mB;
        mA = a * tm;
        mB = mB - K1 * tm;
        // d' = A*d + K*z (both axes at once)
        const f2 s = dp + dv;
        dp = a * s + K0 * z;
        dv = dv + K1 * (z - s);
    }

    // ---- write chunk map: [chunk][track][8]
    float* w = ws + ((size_t)chunk * KF_NT + track) * 8;
    *(float4*)(w)     = make_float4(mA.x, mA.y, mB.x, mB.y);
    *(float4*)(w + 4) = make_float4(dp.x, dp.y, dv.x, dv.y);
}

__global__ __launch_bounds__(64) void kf_compose(const float* __restrict__ ws,
                                                 float* __restrict__ out) {
    const int track = blockIdx.x * 64 + threadIdx.x;   // 0..32767
    f2 x = {0.f, 0.f};   // (x0, x1)
    f2 v = {0.f, 0.f};   // (v0, v1)
#pragma unroll
    for (int c = 0; c < KF_C; ++c) {
        const float* w = ws + ((size_t)c * KF_NT + track) * 8;
        const float4 a = *(const float4*)(w);
        const float4 d = *(const float4*)(w + 4);
        const f2 dpv = {d.x, d.y};
        const f2 dvv = {d.z, d.w};
        const f2 nx = a.x * x + a.y * v + dpv;
        const f2 nv = a.z * x + a.w * v + dvv;
        x = nx; v = nv;
    }
    float* o = out + (size_t)track * 3;
    o[0] = 1.0f;
    o[1] = x.x;
    o[2] = x.y;
}

extern "C" void kernel_launch(void* const* d_in, const int* in_sizes, int n_in,
                              void* d_out, int out_size, void* d_ws, size_t ws_size,
                              hipStream_t stream) {
    (void)in_sizes; (void)n_in; (void)ws_size; (void)out_size;
    const float* batch = (const float*)d_in[0];
    float* out = (float*)d_out;
    float* ws = (float*)d_ws;   // needs KF_C*KF_NT*8*4 = 16.8 MB

    kf_scan<<<KF_C * KF_NG, 64, 0, stream>>>(batch, ws);     // 8192 blocks
    kf_compose<<<KF_NG, 64, 0, stream>>>(ws, out);           // 512 blocks
}

// Round 13
// 153.705 us; speedup vs baseline: 1.4895x; 1.0136x over previous
//
#include <hip/hip_runtime.h>
#include <stdint.h>

// Kalman filter scan: B=128, T=256, V=256. Fully-fused T-parallel affine-scan.
//
// R12 lesson: ~4 TB/s demand service is invariant to occupancy AND placement;
// the problem is the DEMAND VOLUME -- warm-up re-reads ~100MB that neighboring
// chunks are already reading. Fix: intra-block label sharing.
//
// One 1024-thread block = 16 waves = the 16 chunks of one 64-track group:
//   P1: wave w loads its chunk once (48 indep dword loads/thread, big MLP),
//       keeps label+z in regs, stashes LABELS in LDS (64 KB).
//   P2: wave w warm-ups from wave w-1's labels OUT OF LDS (zero global
//       traffic). Wave 1 = exact replay from true P0; waves>=2 = R11-validated
//       local warm-up (Riccati contraction ~0.15/observed step; measured
//       absmax 0.0078 << 0.063 threshold).
//   P3: real steps from registers (packed-f2 axis math).
//   P4/P5: maps -> LDS (stride 9: 2-way bank alias = free), wave 0 composes
//       all 16 chunk maps per track and writes (1,x,y) directly.
// Global traffic = exactly one input read (100.7 MB) + 0.4 MB out.
// Compose kernel + 33 MB of workspace traffic: eliminated.

#define KF_B 128
#define KF_T 256
#define KF_V 256
#define KF_C 16    // chunks = waves per block
#define KF_L 16    // steps per chunk
#define KF_NT (KF_B * KF_V)   // 32768 tracks
#define KF_NG (KF_NT / 64)    // 512 track-groups = blocks

typedef float f2 __attribute__((ext_vector_type(2)));

// --- P/K recursion shared by warm-up and real steps (identical fp ops) ---
#define KF_PK(label)                                                    \
    const float q00 = p00 + 2.f * p01 + p11 + 0.01f;                    \
    const float q01 = p01 + p11;                                        \
    const float q11 = p11 + 0.01f;                                      \
    const float S = q00 + 1.f;                                          \
    const float m = ((label) != -1.0f) ? 1.0f : 0.0f;                   \
    const float is = m * __builtin_amdgcn_rcpf(S);                      \
    const float K0 = q00 * is;                                          \
    const float K1 = q01 * is;                                          \
    p00 = q00 - K0 * q00;                                               \
    p01 = q01 - K0 * q01;                                               \
    p11 = q11 - K1 * q01;

__global__ __launch_bounds__(1024, 4) void kf_fused(const float* __restrict__ batch,
                                                    float* __restrict__ out) {
    // LDS: phase 1-2 = labels[chunk][t][lane] (16*16*64 fl = 64 KB);
    // phase 4-5 = maps[chunk][lane][9 padded] (9216 fl, reused region).
    __shared__ float lds[KF_C * KF_L * 64];

    const int lane = threadIdx.x & 63;
    const int w    = threadIdx.x >> 6;        // wave index = chunk, 0..15
    const int track = blockIdx.x * 64 + lane; // 0..32767
    const int b = track >> 8;
    const int v = track & (KF_V - 1);

    const int stride = KF_V * 3;              // 768 floats per t
    const float* __restrict__ base =
        batch + ((size_t)b * KF_T * KF_V + v) * 3;
    const float* __restrict__ pc = base + (size_t)(w * KF_L) * stride;

    // ---- phase 1: load own chunk once; labels -> LDS; label+z -> regs ----
    float lab[KF_L];
    f2 z[KF_L];
#pragma unroll
    for (int t = 0; t < KF_L; ++t) {
        const float* q = pc + t * stride;
        lab[t] = q[0];
        z[t].x = q[1];
        z[t].y = q[2];
        lds[(w * KF_L + t) * 64 + lane] = lab[t];
    }
    __syncthreads();

    // covariance recursion state (shared by both axes)
    float p00 = 1000.f, p01 = 0.f, p11 = 1000.f;

    // ---- phase 2: warm-up from previous chunk's labels (LDS) ----
    if (w != 0) {
#pragma unroll
        for (int t = 0; t < KF_L; ++t) {
            const float label = lds[((w - 1) * KF_L + t) * 64 + lane];
            KF_PK(label);
        }
    }

    // ---- phase 3: real steps, accumulate chunk affine map ----
    f2 mA = {1.f, 0.f};   // (m00, m01)
    f2 mB = {0.f, 1.f};   // (m10, m11)
    f2 dp = {0.f, 0.f};   // position offset, both axes
    f2 dv = {0.f, 0.f};   // velocity offset, both axes
#pragma unroll
    for (int t = 0; t < KF_L; ++t) {
        const float label = lab[t];
        const f2 zz = z[t];
        KF_PK(label);
        const float a = 1.f - K0;
        const f2 tm = mA + mB;       // M' = A*M, A=[[a,a],[-K1,1-K1]]
        mA = a * tm;
        mB = mB - K1 * tm;
        const f2 s = dp + dv;        // d' = A*d + K*z
        dp = a * s + K0 * zz;
        dv = dv + K1 * (zz - s);
    }

    // ---- phase 4: publish maps to LDS (reuse; stride 9 kills conflicts) ----
    __syncthreads();   // everyone done reading labels
    {
        float* mp = &lds[(w * 64 + lane) * 9];
        mp[0] = mA.x; mp[1] = mA.y; mp[2] = mB.x; mp[3] = mB.y;
        mp[4] = dp.x; mp[5] = dp.y; mp[6] = dv.x; mp[7] = dv.y;
    }
    __syncthreads();

    // ---- phase 5: wave 0 composes the 16 maps per track, writes output ----
    if (w == 0) {
        f2 x = {0.f, 0.f};
        f2 vv = {0.f, 0.f};
#pragma unroll
        for (int c = 0; c < KF_C; ++c) {
            const float* q = &lds[(c * 64 + lane) * 9];
            const float a00 = q[0], a01 = q[1], a10 = q[2], a11 = q[3];
            const f2 dpp = {q[4], q[5]};
            const f2 dvv = {q[6], q[7]};
            const f2 nx = a00 * x + a01 * vv + dpp;
            const f2 nv = a10 * x + a11 * vv + dvv;
            x = nx; vv = nv;
        }
        float* o = out + (size_t)track * 3;
        o[0] = 1.0f;
        o[1] = x.x;
        o[2] = x.y;
    }
}

extern "C" void kernel_launch(void* const* d_in, const int* in_sizes, int n_in,
                              void* d_out, int out_size, void* d_ws, size_t ws_size,
                              hipStream_t stream) {
    (void)in_sizes; (void)n_in; (void)d_ws; (void)ws_size; (void)out_size;
    const float* batch = (const float*)d_in[0];
    float* out = (float*)d_out;
    kf_fused<<<KF_NG, 1024, 0, stream>>>(batch, out);   // 512 blocks x 16 waves
}